// Round 4
// baseline (398.853 us; speedup 1.0000x reference)
//
#include <hip/hip_runtime.h>

// Trilinear feature interpolation:
//   out[n,f] = sum_{k=0..7} clamp(coeffs[n,k],0,1) * features[corner_idx[n,k], f]
// N = 1e6, V = 1e6, F = 32.
//
// Round 4: rounds 1-3 pinned at 191 us regardless of scheduling (VGPR=28 all
// three) -> gather pipe is rate-limited by unique-cacheline/divergent-lane
// processing + HBM random re-fetch (FETCH 517 MB vs 192 MB compulsory; the
// 128 MB fp32 table + 190 MB streams thrash L3).
// Fix: pass 1 converts the table to bf16 (64 MB) in d_ws; pass 2 gathers
// 64 B rows with 4 lanes x 16 B per query. Halves lanes/lines/bytes per
// gather and makes the table L3-resident.

constexpr int F = 32;

__device__ __forceinline__ unsigned pack_bf16_2(float a, float b) {
    unsigned ua = __float_as_uint(a);
    unsigned ub = __float_as_uint(b);
    ua = (ua + 0x7fffu + ((ua >> 16) & 1u)) >> 16;          // RN-even
    ub = (ub + 0x7fffu + ((ub >> 16) & 1u)) >> 16;
    return ua | (ub << 16);
}

__device__ __forceinline__ float bf16_lo(unsigned u) {
    return __uint_as_float(u << 16);
}
__device__ __forceinline__ float bf16_hi(unsigned u) {
    return __uint_as_float(u & 0xffff0000u);
}

// Pass 1: fp32 [V,32] -> bf16 [V,32] (as uint4 rows of 16 B; row = 64 B).
__global__ __launch_bounds__(256) void SPC_convert_kernel(
    const float4* __restrict__ in, uint4* __restrict__ out, int n_groups)
{
    int i = blockIdx.x * 256 + threadIdx.x;   // one group = 8 floats = 1 uint4
    if (i >= n_groups) return;
    float4 a = in[(size_t)i * 2];
    float4 b = in[(size_t)i * 2 + 1];
    uint4 r;
    r.x = pack_bf16_2(a.x, a.y);
    r.y = pack_bf16_2(a.z, a.w);
    r.z = pack_bf16_2(b.x, b.y);
    r.w = pack_bf16_2(b.z, b.w);
    out[i] = r;
}

// Pass 2: gather-interpolate from bf16 table. 256 threads = 64 queries,
// thread t -> (query t/4, feature group t%4 of 8). Each (query,corner)
// gather = one 64 B line covered by 4 lanes x uint4.
__global__ __launch_bounds__(256) void SPC_gather_bf16_kernel(
    const float* __restrict__ coeffs,      // [N,8]
    const int*   __restrict__ corner_idx,  // [N,8]
    const uint4* __restrict__ feat,        // [V,4] uint4 (bf16 rows)
    float*       __restrict__ out,         // [N,32]
    int N)
{
    __shared__ int   s_idx[512];
    __shared__ float s_c[512];

    const int t = threadIdx.x;
    const long long base  = (long long)blockIdx.x * 512;
    const long long total = (long long)N * 8;

    long long p0 = base + t, p1 = base + t + 256;
    s_idx[t]       = (p0 < total) ? corner_idx[p0] : 0;
    s_c[t]         = (p0 < total) ? coeffs[p0]     : 0.0f;
    s_idx[t + 256] = (p1 < total) ? corner_idx[p1] : 0;
    s_c[t + 256]   = (p1 < total) ? coeffs[p1]     : 0.0f;
    __syncthreads();

    const int q_local = t >> 2;          // 0..63
    const int g       = t & 3;           // 0..3, 8 features each
    const long long n = (long long)blockIdx.x * 64 + q_local;
    if (n >= N) return;

    const int qb = q_local << 3;
    float acc0 = 0.f, acc1 = 0.f, acc2 = 0.f, acc3 = 0.f;
    float acc4 = 0.f, acc5 = 0.f, acc6 = 0.f, acc7 = 0.f;

    #pragma unroll
    for (int k = 0; k < 8; ++k) {
        const uint4 u = feat[(size_t)s_idx[qb + k] * 4 + g];
        float c = s_c[qb + k];
        c = fminf(fmaxf(c, 0.0f), 1.0f);
        acc0 = fmaf(c, bf16_lo(u.x), acc0);
        acc1 = fmaf(c, bf16_hi(u.x), acc1);
        acc2 = fmaf(c, bf16_lo(u.y), acc2);
        acc3 = fmaf(c, bf16_hi(u.y), acc3);
        acc4 = fmaf(c, bf16_lo(u.z), acc4);
        acc5 = fmaf(c, bf16_hi(u.z), acc5);
        acc6 = fmaf(c, bf16_lo(u.w), acc6);
        acc7 = fmaf(c, bf16_hi(u.w), acc7);
    }

    float* o = out + (size_t)n * F + (g << 3);
    *reinterpret_cast<float4*>(o)     = make_float4(acc0, acc1, acc2, acc3);
    *reinterpret_cast<float4*>(o + 4) = make_float4(acc4, acc5, acc6, acc7);
}

// Fallback (ws too small): round-1 fp32 gather, known-correct at 191 us.
__global__ __launch_bounds__(256) void SPC_gather_fp32_kernel(
    const float* __restrict__ coeffs,
    const int*   __restrict__ corner_idx,
    const float* __restrict__ features,
    float*       __restrict__ out,
    int N)
{
    __shared__ int   s_idx[256];
    __shared__ float s_c[256];
    const int t  = threadIdx.x;
    const int q0 = blockIdx.x * 32;
    const long long load_pos = (long long)q0 * 8 + t;
    if (load_pos < (long long)N * 8) {
        s_idx[t] = corner_idx[load_pos];
        s_c[t]   = coeffs[load_pos];
    } else { s_idx[t] = 0; s_c[t] = 0.0f; }
    __syncthreads();
    const int q_local = t >> 3, g = t & 7;
    const int n = q0 + q_local;
    if (n >= N) return;
    float4 acc = make_float4(0.f, 0.f, 0.f, 0.f);
    #pragma unroll
    for (int k = 0; k < 8; ++k) {
        const int idx = s_idx[(q_local << 3) + k];
        float c = s_c[(q_local << 3) + k];
        c = fminf(fmaxf(c, 0.0f), 1.0f);
        const float4 f4 = *reinterpret_cast<const float4*>(
            features + (size_t)idx * F + (g << 2));
        acc.x = fmaf(c, f4.x, acc.x);
        acc.y = fmaf(c, f4.y, acc.y);
        acc.z = fmaf(c, f4.z, acc.z);
        acc.w = fmaf(c, f4.w, acc.w);
    }
    *reinterpret_cast<float4*>(out + (size_t)n * F + (g << 2)) = acc;
}

extern "C" void kernel_launch(void* const* d_in, const int* in_sizes, int n_in,
                              void* d_out, int out_size, void* d_ws, size_t ws_size,
                              hipStream_t stream) {
    const float* coeffs     = (const float*)d_in[0];   // [N,8] fp32
    const int*   corner_idx = (const int*)d_in[1];     // [N,8] int32
    const float* features   = (const float*)d_in[2];   // [V,32] fp32
    float*       out        = (float*)d_out;           // [N,32] fp32

    const int N = in_sizes[0] / 8;
    const int V = in_sizes[2] / F;
    const size_t ws_needed = (size_t)V * F * 2;        // bf16 table

    if (ws_size >= ws_needed) {
        const int n_groups = (V * F) / 8;              // 32M/8 = 4M
        SPC_convert_kernel<<<(n_groups + 255) / 256, 256, 0, stream>>>(
            (const float4*)features, (uint4*)d_ws, n_groups);

        const int blocks = (N + 63) / 64;
        SPC_gather_bf16_kernel<<<blocks, 256, 0, stream>>>(
            coeffs, corner_idx, (const uint4*)d_ws, out, N);
    } else {
        const int blocks = (N + 31) / 32;
        SPC_gather_fp32_kernel<<<blocks, 256, 0, stream>>>(
            coeffs, corner_idx, features, out, N);
    }
}